// Round 7
// baseline (4324.103 us; speedup 1.0000x reference)
//
#include <hip/hip_runtime.h>

typedef unsigned short u16;
typedef unsigned int   u32;
typedef unsigned long long u64;
typedef __attribute__((ext_vector_type(4))) float f32x4;
typedef __attribute__((ext_vector_type(8))) short short8;
typedef __attribute__((ext_vector_type(8))) __bf16 bf16x8v;
typedef __attribute__((ext_vector_type(4))) u32 u32x4;

// ---------- bf16 helpers (manual, RNE) ----------
__device__ __forceinline__ float bf2f(u16 v) { return __uint_as_float(((u32)v) << 16); }
__device__ __forceinline__ u16 f2bf(float f) {
    u32 u = __float_as_uint(f);
    u32 r = (u + 0x7fffu + ((u >> 16) & 1u)) >> 16;
    return (u16)r;
}
__device__ __forceinline__ float sigm(float x) { return 1.f / (1.f + __expf(-x)); }
__device__ __forceinline__ float tanh_f(float x) { return 1.f - 2.f / (__expf(2.f * x) + 1.f); }

// ---------- MFMA wrapper ----------
template <class A>
__device__ __forceinline__ auto try_mfma(A a, A b, f32x4 c, int)
    -> decltype(__builtin_amdgcn_mfma_f32_16x16x32_bf16(a, b, c, 0, 0, 0)) {
    return __builtin_amdgcn_mfma_f32_16x16x32_bf16(a, b, c, 0, 0, 0);
}
template <class A>
__device__ __forceinline__ f32x4 try_mfma(A a, A b, f32x4 c, long) {
    return __builtin_amdgcn_mfma_f32_16x16x32_bf16(
        __builtin_bit_cast(bf16x8v, a), __builtin_bit_cast(bf16x8v, b), c, 0, 0, 0);
}
__device__ __forceinline__ f32x4 MFMA(short8 a, short8 b, f32x4 c) { return try_mfma(a, b, c, 0); }

// ---------- coherent VMEM asm primitives (all loop VMEM is asm => exact vmcnt ledger) ----------
__device__ __forceinline__ void cload4_issue(const u32* p0, const u32* p1, const u32* p2, const u32* p3,
                                             u32x4& a, u32x4& b, u32x4& c, u32x4& d) {
    asm volatile("global_load_dwordx4 %0, %4, off sc0 sc1\n\t"
                 "global_load_dwordx4 %1, %5, off sc0 sc1\n\t"
                 "global_load_dwordx4 %2, %6, off sc0 sc1\n\t"
                 "global_load_dwordx4 %3, %7, off sc0 sc1"
                 : "=&v"(a), "=&v"(b), "=&v"(c), "=&v"(d)
                 : "v"(p0), "v"(p1), "v"(p2), "v"(p3)
                 : "memory");
}
__device__ __forceinline__ void gxload4(const u16* p0, const u16* p1, const u16* p2, const u16* p3,
                                        u32& a, u32& b, u32& c, u32& d) {
    asm volatile("global_load_ushort %0, %4, off\n\t"
                 "global_load_ushort %1, %5, off\n\t"
                 "global_load_ushort %2, %6, off\n\t"
                 "global_load_ushort %3, %7, off"
                 : "=&v"(a), "=&v"(b), "=&v"(c), "=&v"(d)
                 : "v"(p0), "v"(p1), "v"(p2), "v"(p3)
                 : "memory");
}
__device__ __forceinline__ void cstore1(u32* p, u32 v) {
    asm volatile("global_store_dword %0, %1, off sc0 sc1" :: "v"(p), "v"(v) : "memory");
}
__device__ __forceinline__ void store_short(u16* p, u32 v) {
    asm volatile("global_store_short %0, %1, off" :: "v"(p), "v"(v) : "memory");
}

// counted wait: N = #VMEM ops issued after the 4 poll loads (ties gx regs too so
// their uses can't be hoisted above the wait)
#define WAITVM_TIE(IMM, a, b, c, d, g0, g1, g2, g3)                                   \
    do {                                                                              \
        asm volatile("s_waitcnt vmcnt(" IMM ")"                                       \
                     : "+v"(a), "+v"(b), "+v"(c), "+v"(d),                            \
                       "+v"(g0), "+v"(g1), "+v"(g2), "+v"(g3)::"memory");             \
        __builtin_amdgcn_sched_barrier(0);                                            \
    } while (0)
#define WAITVM0(a, b, c, d)                                                           \
    do {                                                                              \
        asm volatile("s_waitcnt vmcnt(0)" : "+v"(a), "+v"(b), "+v"(c), "+v"(d)::"memory"); \
        __builtin_amdgcn_sched_barrier(0);                                            \
    } while (0)

// B=64, S=1024, H=512 fixed.

// ---------- prep ----------
__global__ void k_prep(const float* __restrict__ w_ih, const float* __restrict__ w_hh,
                       const float* __restrict__ b_ih, const float* __restrict__ b_hh,
                       const float* __restrict__ w1, const float* __restrict__ w2,
                       u16* __restrict__ wihb, u16* __restrict__ whhb,
                       u16* __restrict__ w1t, u16* __restrict__ w2t, float* __restrict__ biasc) {
    for (u32 i = blockIdx.x * blockDim.x + threadIdx.x; i < 3147776u; i += gridDim.x * blockDim.x) {
        if (i < 1048576u) { wihb[i] = f2bf(w_ih[i]); }
        else if (i < 2097152u) { u32 j = i - 1048576u; whhb[j] = f2bf(w_hh[j]); }
        else if (i < 2621440u) { u32 j = i - 2097152u; u32 n = j >> 9,  k = j & 511u;  w1t[j] = f2bf(w1[k * 1024u + n]); }
        else if (i < 3145728u) { u32 j = i - 2621440u; u32 n = j >> 10, k = j & 1023u; w2t[j] = f2bf(w2[k * 512u + n]); }
        else { u32 j = i - 3145728u; biasc[j] = b_ih[j] + b_hh[j]; }
    }
}

// ---------- init: zero tagged exchange buffer (tag0 == h(0)=0) ----------
__global__ void k_init(u32* __restrict__ h_ex) {
    u32 i = blockIdx.x * blockDim.x + threadIdx.x;
    if (i < 65536u) h_ex[i] = 0u;
}

// ---------- LayerNorm ----------
__global__ __launch_bounds__(256) void k_pre_ln(const float* __restrict__ x,
                                                const float* __restrict__ g, const float* __restrict__ b,
                                                u16* __restrict__ out) {
    const int row = blockIdx.x * 4 + (threadIdx.x >> 6);
    const int lane = threadIdx.x & 63;
    const float* xr = x + (size_t)row * 512 + lane * 8;
    float v[8];
    *(float4*)(v)     = *(const float4*)(xr);
    *(float4*)(v + 4) = *(const float4*)(xr + 4);
    float s = 0.f, q = 0.f;
#pragma unroll
    for (int e = 0; e < 8; ++e) { s += v[e]; q += v[e] * v[e]; }
#pragma unroll
    for (int o = 32; o; o >>= 1) { s += __shfl_xor(s, o); q += __shfl_xor(q, o); }
    float mu = s * (1.f / 512.f);
    float rs = rsqrtf(q * (1.f / 512.f) - mu * mu + 1e-5f);
    short8 ov;
#pragma unroll
    for (int e = 0; e < 8; ++e) {
        int cidx = lane * 8 + e;
        ov[e] = (short)f2bf((v[e] - mu) * rs * g[cidx] + b[cidx]);
    }
    *(short8*)(out + (size_t)row * 512 + lane * 8) = ov;
}

__global__ __launch_bounds__(256) void k_res_ln(const float* __restrict__ x, const u16* __restrict__ r,
                                                const float* __restrict__ g, const float* __restrict__ b,
                                                u16* __restrict__ out) {
    const int row = blockIdx.x * 4 + (threadIdx.x >> 6);
    const int lane = threadIdx.x & 63;
    const float* xr = x + (size_t)row * 512 + lane * 8;
    short8 rv = *(const short8*)(r + (size_t)row * 512 + lane * 8);
    float v[8];
    *(float4*)(v)     = *(const float4*)(xr);
    *(float4*)(v + 4) = *(const float4*)(xr + 4);
#pragma unroll
    for (int e = 0; e < 8; ++e) v[e] += bf2f((u16)rv[e]);
    float s = 0.f, q = 0.f;
#pragma unroll
    for (int e = 0; e < 8; ++e) { s += v[e]; q += v[e] * v[e]; }
#pragma unroll
    for (int o = 32; o; o >>= 1) { s += __shfl_xor(s, o); q += __shfl_xor(q, o); }
    float mu = s * (1.f / 512.f);
    float rs = rsqrtf(q * (1.f / 512.f) - mu * mu + 1e-5f);
    short8 ov;
#pragma unroll
    for (int e = 0; e < 8; ++e) {
        int cidx = lane * 8 + e;
        ov[e] = (short)f2bf((v[e] - mu) * rs * g[cidx] + b[cidx]);
    }
    *(short8*)(out + (size_t)row * 512 + lane * 8) = ov;
}

// ---------- GEMM (B^T layout), global_load_lds staging (unchanged from R6) ----------
template <int KD, int EPI>
__global__ __launch_bounds__(256, 2)
void k_gemm(const u16* __restrict__ A, const u16* __restrict__ B,
            const float* __restrict__ bias, u16* __restrict__ Cb, float* __restrict__ Cf,
            const float* __restrict__ Xres, const u16* __restrict__ Rres, int N) {
    __shared__ __align__(16) u16 At[128 * 64];
    __shared__ __align__(16) u16 Bt[128 * 64];
    const int tid = threadIdx.x;
    const int lane = tid & 63, wv = tid >> 6;
    const int m0 = blockIdx.y << 7, n0 = blockIdx.x << 7;
    const int wm = (wv >> 1) << 6, wn = (wv & 1) << 6;
    f32x4 acc[4][4] = {};
    const int rr = tid >> 3, kb = tid & 7;
    const int ksw = (kb ^ (rr & 7)) * 8;
    const int wvb = wv * 512;

    for (int k0 = 0; k0 < KD; k0 += 64) {
#pragma unroll
        for (int r = 0; r < 4; ++r) {
            const u16* sa = A + (size_t)(m0 + r * 32 + rr) * KD + (k0 + ksw);
            const u16* sb = B + (size_t)(n0 + r * 32 + rr) * KD + (k0 + ksw);
            __builtin_amdgcn_global_load_lds((const u32*)sa, (u32*)&At[r * 2048 + wvb], 16, 0, 0);
            __builtin_amdgcn_global_load_lds((const u32*)sb, (u32*)&Bt[r * 2048 + wvb], 16, 0, 0);
        }
        __syncthreads();
#pragma unroll
        for (int ks = 0; ks < 2; ++ks) {
            short8 af[4], bf[4];
#pragma unroll
            for (int mt = 0; mt < 4; ++mt) {
                int rowa = wm + mt * 16 + (lane & 15);
                int kba = ((lane >> 4) * 16 + ks * 64) ^ ((rowa & 7) << 4);
                af[mt] = *(const short8*)((const char*)At + rowa * 128 + kba);
                int rowb = wn + mt * 16 + (lane & 15);
                int kbb = ((lane >> 4) * 16 + ks * 64) ^ ((rowb & 7) << 4);
                bf[mt] = *(const short8*)((const char*)Bt + rowb * 128 + kbb);
            }
#pragma unroll
            for (int mt = 0; mt < 4; ++mt)
#pragma unroll
                for (int nt = 0; nt < 4; ++nt)
                    acc[mt][nt] = MFMA(af[mt], bf[nt], acc[mt][nt]);
        }
        __syncthreads();
    }
#pragma unroll
    for (int mt = 0; mt < 4; ++mt) {
#pragma unroll
        for (int nt = 0; nt < 4; ++nt) {
            int gn = n0 + wn + nt * 16 + (lane & 15);
            float bi = bias[gn];
#pragma unroll
            for (int i = 0; i < 4; ++i) {
                int gm = m0 + wm + mt * 16 + (lane >> 4) * 4 + i;
                float v = acc[mt][nt][i] + bi;
                size_t idx = (size_t)gm * (size_t)N + gn;
                if constexpr (EPI == 0) {
                    Cb[idx] = f2bf(v);
                } else if constexpr (EPI == 1) {
                    v = 0.5f * v * (1.f + erff(v * 0.70710678118f));
                    Cb[idx] = f2bf(v);
                } else {
                    Cf[idx] = v + Xres[idx] + bf2f(Rres[idx]);
                }
            }
        }
    }
}

// ---------- LSTM scan helpers ----------
__device__ __forceinline__ void poll_retry(const u32* bse, u32 t, u32x4& a, u32x4& b, u32x4& c, u32x4& d) {
    int tries = 0;
    for (;;) {
        u32 bad = 0;
#pragma unroll
        for (int e = 0; e < 4; ++e) {
            bad |= (a[e] >> 16) ^ t;
            bad |= (b[e] >> 16) ^ t;
            bad |= (c[e] >> 16) ^ t;
            bad |= (d[e] >> 16) ^ t;
        }
        if (!bad) return;
        if (tries++) __builtin_amdgcn_s_sleep(1);
        cload4_issue(bse, bse + 2048, bse + 4096, bse + 6144, a, b, c, d);
        WAITVM0(a, b, c, d);
    }
}

__device__ __forceinline__ void lds_pack(u16* hlds, const int* lofs,
                                         const u32x4& a, const u32x4& b, const u32x4& c, const u32x4& d) {
    char* base = (char*)hlds;
    u32 a0 = (a[0] & 0xffffu) | (a[1] << 16), a1 = (a[2] & 0xffffu) | (a[3] << 16);
    u32 b0 = (b[0] & 0xffffu) | (b[1] << 16), b1 = (b[2] & 0xffffu) | (b[3] << 16);
    u32 c0 = (c[0] & 0xffffu) | (c[1] << 16), c1 = (c[2] & 0xffffu) | (c[3] << 16);
    u32 d0 = (d[0] & 0xffffu) | (d[1] << 16), d1 = (d[2] & 0xffffu) | (d[3] << 16);
    *(u64*)(base + lofs[0]) = (u64)a0 | ((u64)a1 << 32);
    *(u64*)(base + lofs[1]) = (u64)b0 | ((u64)b1 << 32);
    *(u64*)(base + lofs[2]) = (u64)c0 | ((u64)c1 << 32);
    *(u64*)(base + lofs[3]) = (u64)d0 | ((u64)d1 << 32);
}

__device__ __forceinline__ void mfma_phase(const u16* hlds, const short8* wf, const u32* gxv,
                                           int lane, int lc, float* g_buf) {
    f32x4 a0 = {}, a1 = {}, a2 = {}, a3 = {};
    const int rowa = lane & 15;
    const int kb0 = (lane >> 4) * 16;
    const int sw = (rowa & 7) << 4;
    const char* rb_ = (const char*)hlds + rowa * 1024;
#pragma unroll
    for (int ks = 0; ks < 4; ++ks) {
        a0 = MFMA(*(const short8*)(rb_ + ((kb0 + (4 * ks + 0) * 64) ^ sw)), wf[4 * ks + 0], a0);
        a1 = MFMA(*(const short8*)(rb_ + ((kb0 + (4 * ks + 1) * 64) ^ sw)), wf[4 * ks + 1], a1);
        a2 = MFMA(*(const short8*)(rb_ + ((kb0 + (4 * ks + 2) * 64) ^ sw)), wf[4 * ks + 2], a2);
        a3 = MFMA(*(const short8*)(rb_ + ((kb0 + (4 * ks + 3) * 64) ^ sw)), wf[4 * ks + 3], a3);
    }
    f32x4 acc = (a0 + a1) + (a2 + a3);
#pragma unroll
    for (int i = 0; i < 4; ++i)
        g_buf[lc * 17 + ((lane >> 4) * 4 + i)] = acc[i] + bf2f((u16)gxv[i]);
}

__device__ __forceinline__ void gates_phase(float& cst, const float* g_buf, int b_own, int jj,
                                            u32* pubp, u16* routp, u32 tag1) {
    float iv = g_buf[jj * 17 + b_own];
    float fv = g_buf[(jj + 32) * 17 + b_own];
    float gv = g_buf[(jj + 64) * 17 + b_own];
    float ov = g_buf[(jj + 96) * 17 + b_own];
    cst = sigm(fv) * cst + sigm(iv) * tanh_f(gv);
    float h = sigm(ov) * tanh_f(cst);
    u16 hb = f2bf(h);
    cstore1(pubp, (tag1 << 16) | (u32)hb);
    store_short(routp, (u32)hb);
}

// ---------- LSTM scan: 32 WGs x 512 thr; TWO chains per WG (groups 2p, 2p+1, same slice).
// wf (W_hh cols) shared by both chains. Counted-vmcnt ledger per period:
//   ph2: PB(4) | ph3: gxA(4) | ph4: SA,RA | ph5 wait vmcnt(6)
//   ph6: PA(4) | ph7: gxB(4) | ph8: SB,RB | ph1 wait vmcnt(6)   (first period: vmcnt(4))
// Tag monotonicity makes any under-wait self-correcting (stale tag -> retry+vmcnt(0)).
__global__ __launch_bounds__(512, 1)
void k_scan(const u16* __restrict__ gx, const u16* __restrict__ whh,
            u16* __restrict__ rout, u32* __restrict__ h_ex) {
    const int sl = blockIdx.x & 15;
    const int pr = blockIdx.x >> 4;
    const int gA = pr * 2, gB = pr * 2 + 1;
    const int tid = threadIdx.x;
    const int lane = tid & 63, wv = tid >> 6;
    const int gt = wv >> 1, jb = wv & 1;
    const int cb = gt * 512 + sl * 32 + jb * 16;

    __shared__ __align__(16) u16 hldsA[16 * 512];
    __shared__ __align__(16) u16 hldsB[16 * 512];
    __shared__ float g_buf[128 * 17];

    short8 wf[16];
    {
        const u16* wp = whh + (size_t)(cb + (lane & 15)) * 512 + (lane >> 4) * 8;
#pragma unroll
        for (int ks = 0; ks < 16; ++ks) wf[ks] = *(const short8*)(wp + ks * 32);
    }
    const int b_own = tid >> 5, jj = tid & 31;
    float cstA = 0.f, cstB = 0.f;
    u32* hexA = h_ex + (u32)gA * 16384u;
    u32* hexB = h_ex + (u32)gB * 16384u;
    const int lc = gt * 32 + jb * 16 + (lane & 15);
    const int ngl = cb + (lane & 15);
    const u32 pub_idx = (u32)(b_own * 512 + sl * 32 + jj);

    const int jbyte = (tid & 127) * 8;
    int lofs[4];
#pragma unroll
    for (int q = 0; q < 4; ++q) {
        int bq = q * 4 + (tid >> 7);
        lofs[q] = bq * 1024 + (jbyte ^ ((bq & 7) << 4));
    }
    const u16 *gpA[4], *gpB[4];
#pragma unroll
    for (int i = 0; i < 4; ++i) {
        int bi = (lane >> 4) * 4 + i;
        gpA[i] = gx + (size_t)(gA * 16 + bi) * 1024 * 2048 + ngl;
        gpB[i] = gx + (size_t)(gB * 16 + bi) * 1024 * 2048 + ngl;
    }
    u16* rpA = rout + (size_t)(gA * 16 + b_own) * 1024 * 512 + sl * 32 + jj;
    u16* rpB = rout + (size_t)(gB * 16 + b_own) * 1024 * 512 + sl * 32 + jj;

    u32 gxA[4], gxB[4];
    u32x4 qa, qb, qc, qd;   // chain A poll regs
    u32x4 ua, ub, uc, ud;   // chain B poll regs

    // prologue: gxA(0)(4) -> PA(0)(4) -> gxB(0)(4)   [ledger: 4 ops younger than PA(0)]
    gxload4(gpA[0], gpA[1], gpA[2], gpA[3], gxA[0], gxA[1], gxA[2], gxA[3]);
    {
        const u32* bse = hexA + tid * 4;  // parity 0
        cload4_issue(bse, bse + 2048, bse + 4096, bse + 6144, qa, qb, qc, qd);
    }
    gxload4(gpB[0], gpB[1], gpB[2], gpB[3], gxB[0], gxB[1], gxB[2], gxB[3]);

    for (u32 t = 0; t < 1024; ++t) {
        const u32 part = (t & 1) * 8192u;
        const u32 parn = ((t + 1) & 1) * 8192u;
        const u32* bA = hexA + part + tid * 4;
        const u32* bB = hexB + part + tid * 4;
        const int adv = (t < 1023) ? 2048 : 0;

        // ---- ph1: wait A(t)
        if (t == 0) { WAITVM_TIE("4", qa, qb, qc, qd, gxA[0], gxA[1], gxA[2], gxA[3]); }
        else        { WAITVM_TIE("6", qa, qb, qc, qd, gxA[0], gxA[1], gxA[2], gxA[3]); }
        poll_retry(bA, t, qa, qb, qc, qd);
        // ---- ph2: LDS_A; issue PB(t)
        lds_pack(hldsA, lofs, qa, qb, qc, qd);
        cload4_issue(bB, bB + 2048, bB + 4096, bB + 6144, ua, ub, uc, ud);
        __syncthreads();
        // ---- ph3: MFMA_A (+gxA(t) into g_buf); issue gxA(t+1)
        mfma_phase(hldsA, wf, gxA, lane, lc, g_buf);
#pragma unroll
        for (int i = 0; i < 4; ++i) gpA[i] += adv;
        gxload4(gpA[0], gpA[1], gpA[2], gpA[3], gxA[0], gxA[1], gxA[2], gxA[3]);
        __syncthreads();
        // ---- ph4: gates A; publish A(t+1); rout A(t)
        gates_phase(cstA, g_buf, b_own, jj, hexA + parn + pub_idx, rpA, t + 1);
        rpA += 512;
        // ---- ph5: wait B(t)
        WAITVM_TIE("6", ua, ub, uc, ud, gxB[0], gxB[1], gxB[2], gxB[3]);
        poll_retry(bB, t, ua, ub, uc, ud);
        // ---- ph6: LDS_B; issue PA(t+1)
        lds_pack(hldsB, lofs, ua, ub, uc, ud);
        {
            const u32* bA2 = hexA + parn + tid * 4;
            cload4_issue(bA2, bA2 + 2048, bA2 + 4096, bA2 + 6144, qa, qb, qc, qd);
        }
        __syncthreads();
        // ---- ph7: MFMA_B; issue gxB(t+1)
        mfma_phase(hldsB, wf, gxB, lane, lc, g_buf);
#pragma unroll
        for (int i = 0; i < 4; ++i) gpB[i] += adv;
        gxload4(gpB[0], gpB[1], gpB[2], gpB[3], gxB[0], gxB[1], gxB[2], gxB[3]);
        __syncthreads();
        // ---- ph8: gates B; publish B(t+1); rout B(t)
        gates_phase(cstB, g_buf, b_own, jj, hexB + parn + pub_idx, rpB, t + 1);
        rpB += 512;
    }
}

// ---------- launch ----------
extern "C" void kernel_launch(void* const* d_in, const int* in_sizes, int n_in,
                              void* d_out, int out_size, void* d_ws, size_t ws_size,
                              hipStream_t stream) {
    const float* x     = (const float*)d_in[0];
    const float* pre_g = (const float*)d_in[1];
    const float* pre_b = (const float*)d_in[2];
    const float* w_ih  = (const float*)d_in[3];
    const float* w_hh  = (const float*)d_in[4];
    const float* b_ih  = (const float*)d_in[5];
    const float* b_hh  = (const float*)d_in[6];
    const float* post_g= (const float*)d_in[7];
    const float* post_b= (const float*)d_in[8];
    const float* w1    = (const float*)d_in[9];
    const float* b1    = (const float*)d_in[10];
    const float* w2    = (const float*)d_in[11];
    const float* b2    = (const float*)d_in[12];
    float* out = (float*)d_out;

    char* p = (char*)d_ws;
    auto carve = [&](size_t bytes) { void* r = (void*)p; p += (bytes + 255) & ~(size_t)255; return r; };
    u16* xln   = (u16*)carve(64ull * 1024 * 512 * 2);    // 64 MiB; reused as ln1 after GEMM1
    u16* gxb   = (u16*)carve(64ull * 1024 * 2048 * 2);   // 256 MiB; reused as h1 after scan
    u16* rb    = (u16*)carve(64ull * 1024 * 512 * 2);    // 64 MiB
    u16* wihb  = (u16*)carve(2048ull * 512 * 2);
    u16* whhb  = (u16*)carve(2048ull * 512 * 2);
    u16* w1t   = (u16*)carve(1024ull * 512 * 2);
    u16* w2t   = (u16*)carve(512ull * 1024 * 2);
    float* biasc = (float*)carve(2048ull * 4);
    u32* h_ex  = (u32*)carve(65536ull * 4);              // 4 groups x 2 parities x 8192 tagged u32
    u16* ln1 = xln;   // alias: xln dead after GEMM1
    u16* h1  = gxb;   // alias: gx dead after scan

    k_prep<<<3072, 256, 0, stream>>>(w_ih, w_hh, b_ih, b_hh, w1, w2, wihb, whhb, w1t, w2t, biasc);
    k_init<<<256, 256, 0, stream>>>(h_ex);
    k_pre_ln<<<16384, 256, 0, stream>>>(x, pre_g, pre_b, xln);
    k_gemm<512, 0><<<dim3(16, 512), 256, 0, stream>>>(xln, wihb, biasc, gxb, nullptr, nullptr, nullptr, 2048);
    k_scan<<<32, 512, 0, stream>>>(gxb, whhb, rb, h_ex);
    k_res_ln<<<16384, 256, 0, stream>>>(x, rb, post_g, post_b, ln1);
    k_gemm<512, 1><<<dim3(8, 512), 256, 0, stream>>>(ln1, w1t, b1, h1, nullptr, nullptr, nullptr, 1024);
    k_gemm<1024, 2><<<dim3(4, 512), 256, 0, stream>>>(h1, w2t, b2, nullptr, out, x, rb, 512);
}

// Round 11
// 3033.627 us; speedup vs baseline: 1.4254x; 1.4254x over previous
//
#include <hip/hip_runtime.h>

typedef unsigned short u16;
typedef unsigned int   u32;
typedef unsigned long long u64;
typedef __attribute__((ext_vector_type(4))) float f32x4;
typedef __attribute__((ext_vector_type(8))) short short8;
typedef __attribute__((ext_vector_type(8))) __bf16 bf16x8v;
typedef __attribute__((ext_vector_type(4))) u32 u32x4;

// ---------- bf16 helpers (manual, RNE) ----------
__device__ __forceinline__ float bf2f(u16 v) { return __uint_as_float(((u32)v) << 16); }
__device__ __forceinline__ u16 f2bf(float f) {
    u32 u = __float_as_uint(f);
    u32 r = (u + 0x7fffu + ((u >> 16) & 1u)) >> 16;
    return (u16)r;
}
__device__ __forceinline__ float sigm(float x) { return 1.f / (1.f + __expf(-x)); }
__device__ __forceinline__ float tanh_f(float x) { return 1.f - 2.f / (__expf(2.f * x) + 1.f); }

// ---------- MFMA wrapper ----------
template <class A>
__device__ __forceinline__ auto try_mfma(A a, A b, f32x4 c, int)
    -> decltype(__builtin_amdgcn_mfma_f32_16x16x32_bf16(a, b, c, 0, 0, 0)) {
    return __builtin_amdgcn_mfma_f32_16x16x32_bf16(a, b, c, 0, 0, 0);
}
template <class A>
__device__ __forceinline__ f32x4 try_mfma(A a, A b, f32x4 c, long) {
    return __builtin_amdgcn_mfma_f32_16x16x32_bf16(
        __builtin_bit_cast(bf16x8v, a), __builtin_bit_cast(bf16x8v, b), c, 0, 0, 0);
}
__device__ __forceinline__ f32x4 MFMA(short8 a, short8 b, f32x4 c) { return try_mfma(a, b, c, 0); }

// ---------- SELF-CONTAINED coherent loads: load + s_waitcnt vmcnt(0) fused in ONE
// asm block. SIInsertWaitcnts cannot see loads inside asm, so any split
// load-asm / wait-asm pattern leaves compiler-inserted copies or spills of the
// result registers UNPROTECTED (reads of in-flight VGPRs -> garbage). That was
// the R8/R10 NaN: high VGPR pressure (wf0+wf1=128) forced such copies. Fusing
// the wait into the same asm removes the hazard at any pressure.
__device__ __forceinline__ void poll_sc0(const u32* p0, const u32* p1, u32x4& a, u32x4& b) {
    asm volatile("global_load_dwordx4 %0, %2, off sc0\n\t"
                 "global_load_dwordx4 %1, %3, off sc0\n\t"
                 "s_waitcnt vmcnt(0)"
                 : "=&v"(a), "=&v"(b) : "v"(p0), "v"(p1) : "memory");
}
__device__ __forceinline__ void poll_sys(const u32* p0, const u32* p1, u32x4& a, u32x4& b) {
    asm volatile("global_load_dwordx4 %0, %2, off sc0 sc1\n\t"
                 "global_load_dwordx4 %1, %3, off sc0 sc1\n\t"
                 "s_waitcnt vmcnt(0)"
                 : "=&v"(a), "=&v"(b) : "v"(p0), "v"(p1) : "memory");
}
// stores have no result registers -> no hazard
__device__ __forceinline__ void cstore_sc0(u32* p, u32 v) {
    asm volatile("global_store_dword %0, %1, off sc0" :: "v"(p), "v"(v) : "memory");
}
__device__ __forceinline__ void cstore_sys(u32* p, u32 v) {
    asm volatile("global_store_dword %0, %1, off sc0 sc1" :: "v"(p), "v"(v) : "memory");
}
__device__ __forceinline__ void store_short(u16* p, u32 v) {
    asm volatile("global_store_short %0, %1, off" :: "v"(p), "v"(v) : "memory");
}

// LDS barrier WITHOUT vmcnt drain: wait+barrier fused in ONE memory-clobbered
// volatile asm (IR memory ops cannot cross it; volatile asm is a scheduling
// boundary). Keeps gx prefetch and publish stores in flight across barriers.
#define LDS_BARRIER()                                                                 \
    do {                                                                              \
        asm volatile("s_waitcnt lgkmcnt(0)\n\ts_barrier" ::: "memory");               \
        __builtin_amdgcn_sched_barrier(0);                                            \
    } while (0)

// B=64, S=1024, H=512 fixed.

// ---------- prep ----------
__global__ void k_prep(const float* __restrict__ w_ih, const float* __restrict__ w_hh,
                       const float* __restrict__ b_ih, const float* __restrict__ b_hh,
                       const float* __restrict__ w1, const float* __restrict__ w2,
                       u16* __restrict__ wihb, u16* __restrict__ whhb,
                       u16* __restrict__ w1t, u16* __restrict__ w2t, float* __restrict__ biasc) {
    for (u32 i = blockIdx.x * blockDim.x + threadIdx.x; i < 3147776u; i += gridDim.x * blockDim.x) {
        if (i < 1048576u) { wihb[i] = f2bf(w_ih[i]); }
        else if (i < 2097152u) { u32 j = i - 1048576u; whhb[j] = f2bf(w_hh[j]); }
        else if (i < 2621440u) { u32 j = i - 2097152u; u32 n = j >> 9,  k = j & 511u;  w1t[j] = f2bf(w1[k * 1024u + n]); }
        else if (i < 3145728u) { u32 j = i - 2621440u; u32 n = j >> 10, k = j & 1023u; w2t[j] = f2bf(w2[k * 512u + n]); }
        else { u32 j = i - 3145728u; biasc[j] = b_ih[j] + b_hh[j]; }
    }
}

// ---------- init: zero tagged exchange buffers (primary + mirror; tag0 == h(0)=0) ----------
__global__ void k_init(u32* __restrict__ h_ex) {
    u32 i = blockIdx.x * blockDim.x + threadIdx.x;
    if (i < 131072u) h_ex[i] = 0u;
}

// ---------- LayerNorm ----------
__global__ __launch_bounds__(256) void k_pre_ln(const float* __restrict__ x,
                                                const float* __restrict__ g, const float* __restrict__ b,
                                                u16* __restrict__ out) {
    const int row = blockIdx.x * 4 + (threadIdx.x >> 6);
    const int lane = threadIdx.x & 63;
    const float* xr = x + (size_t)row * 512 + lane * 8;
    float v[8];
    *(float4*)(v)     = *(const float4*)(xr);
    *(float4*)(v + 4) = *(const float4*)(xr + 4);
    float s = 0.f, q = 0.f;
#pragma unroll
    for (int e = 0; e < 8; ++e) { s += v[e]; q += v[e] * v[e]; }
#pragma unroll
    for (int o = 32; o; o >>= 1) { s += __shfl_xor(s, o); q += __shfl_xor(q, o); }
    float mu = s * (1.f / 512.f);
    float rs = rsqrtf(q * (1.f / 512.f) - mu * mu + 1e-5f);
    short8 ov;
#pragma unroll
    for (int e = 0; e < 8; ++e) {
        int cidx = lane * 8 + e;
        ov[e] = (short)f2bf((v[e] - mu) * rs * g[cidx] + b[cidx]);
    }
    *(short8*)(out + (size_t)row * 512 + lane * 8) = ov;
}

__global__ __launch_bounds__(256) void k_res_ln(const float* __restrict__ x, const u16* __restrict__ r,
                                                const float* __restrict__ g, const float* __restrict__ b,
                                                u16* __restrict__ out) {
    const int row = blockIdx.x * 4 + (threadIdx.x >> 6);
    const int lane = threadIdx.x & 63;
    const float* xr = x + (size_t)row * 512 + lane * 8;
    short8 rv = *(const short8*)(r + (size_t)row * 512 + lane * 8);
    float v[8];
    *(float4*)(v)     = *(const float4*)(xr);
    *(float4*)(v + 4) = *(const float4*)(xr + 4);
#pragma unroll
    for (int e = 0; e < 8; ++e) v[e] += bf2f((u16)rv[e]);
    float s = 0.f, q = 0.f;
#pragma unroll
    for (int e = 0; e < 8; ++e) { s += v[e]; q += v[e] * v[e]; }
#pragma unroll
    for (int o = 32; o; o >>= 1) { s += __shfl_xor(s, o); q += __shfl_xor(q, o); }
    float mu = s * (1.f / 512.f);
    float rs = rsqrtf(q * (1.f / 512.f) - mu * mu + 1e-5f);
    short8 ov;
#pragma unroll
    for (int e = 0; e < 8; ++e) {
        int cidx = lane * 8 + e;
        ov[e] = (short)f2bf((v[e] - mu) * rs * g[cidx] + b[cidx]);
    }
    *(short8*)(out + (size_t)row * 512 + lane * 8) = ov;
}

// ---------- GEMM (B^T layout), global_load_lds staging ----------
template <int KD, int EPI>
__global__ __launch_bounds__(256, 2)
void k_gemm(const u16* __restrict__ A, const u16* __restrict__ B,
            const float* __restrict__ bias, u16* __restrict__ Cb, float* __restrict__ Cf,
            const float* __restrict__ Xres, const u16* __restrict__ Rres, int N) {
    __shared__ __align__(16) u16 At[128 * 64];
    __shared__ __align__(16) u16 Bt[128 * 64];
    const int tid = threadIdx.x;
    const int lane = tid & 63, wv = tid >> 6;
    const int m0 = blockIdx.y << 7, n0 = blockIdx.x << 7;
    const int wm = (wv >> 1) << 6, wn = (wv & 1) << 6;
    f32x4 acc[4][4] = {};
    const int rr = tid >> 3, kb = tid & 7;
    const int ksw = (kb ^ (rr & 7)) * 8;
    const int wvb = wv * 512;

    for (int k0 = 0; k0 < KD; k0 += 64) {
#pragma unroll
        for (int r = 0; r < 4; ++r) {
            const u16* sa = A + (size_t)(m0 + r * 32 + rr) * KD + (k0 + ksw);
            const u16* sb = B + (size_t)(n0 + r * 32 + rr) * KD + (k0 + ksw);
            __builtin_amdgcn_global_load_lds((const u32*)sa, (u32*)&At[r * 2048 + wvb], 16, 0, 0);
            __builtin_amdgcn_global_load_lds((const u32*)sb, (u32*)&Bt[r * 2048 + wvb], 16, 0, 0);
        }
        __syncthreads();
#pragma unroll
        for (int ks = 0; ks < 2; ++ks) {
            short8 af[4], bf[4];
#pragma unroll
            for (int mt = 0; mt < 4; ++mt) {
                int rowa = wm + mt * 16 + (lane & 15);
                int kba = ((lane >> 4) * 16 + ks * 64) ^ ((rowa & 7) << 4);
                af[mt] = *(const short8*)((const char*)At + rowa * 128 + kba);
                int rowb = wn + mt * 16 + (lane & 15);
                int kbb = ((lane >> 4) * 16 + ks * 64) ^ ((rowb & 7) << 4);
                bf[mt] = *(const short8*)((const char*)Bt + rowb * 128 + kbb);
            }
#pragma unroll
            for (int mt = 0; mt < 4; ++mt)
#pragma unroll
                for (int nt = 0; nt < 4; ++nt)
                    acc[mt][nt] = MFMA(af[mt], bf[nt], acc[mt][nt]);
        }
        __syncthreads();
    }
#pragma unroll
    for (int mt = 0; mt < 4; ++mt) {
#pragma unroll
        for (int nt = 0; nt < 4; ++nt) {
            int gn = n0 + wn + nt * 16 + (lane & 15);
            float bi = bias[gn];
#pragma unroll
            for (int i = 0; i < 4; ++i) {
                int gm = m0 + wm + mt * 16 + (lane >> 4) * 4 + i;
                float v = acc[mt][nt][i] + bi;
                size_t idx = (size_t)gm * (size_t)N + gn;
                if constexpr (EPI == 0) {
                    Cb[idx] = f2bf(v);
                } else if constexpr (EPI == 1) {
                    v = 0.5f * v * (1.f + erff(v * 0.70710678118f));
                    Cb[idx] = f2bf(v);
                } else {
                    Cf[idx] = v + Xres[idx] + bf2f(Rres[idx]);
                }
            }
        }
    }
}

// ---------- LSTM scan v4 ----------
// 64 WGs x 512 thr. grp = blockIdx&7 (round-robin WG->XCD co-locates each group's
// 8 slices on ONE XCD), sl = blockIdx>>3. 8 groups x 8 batches; slice owns 64
// h-cols (256 gate-cols, 2 col-sets of 16 per wave -> wf0/wf1). Exchange:
// tagged u32 (tag<<16|bf16), parity double-buffer. Publish: primary sc0 (local
// XCD L2) + mirror sc0sc1 (IF$, always correct). Poll: SYNCHRONOUS fused
// load+wait, sc0 first, escalate to mirror after 3 misses. Own-slice h goes
// straight to LDS (those threads skip polling). gx: plain C++ loads (compiler
// waitcnt), depth-2 double buffer. Barriers: fused lgkm-only (no vmcnt drain).
__global__ __launch_bounds__(512, 1)
void k_scan(const u16* __restrict__ gx, const u16* __restrict__ whh,
            u16* __restrict__ rout, u32* __restrict__ h_ex) {
    const int grp = blockIdx.x & 7, sl = blockIdx.x >> 3;
    const int tid = threadIdx.x;
    const int lane = tid & 63, wv = tid >> 6;
    const int gt = wv >> 1, jh = (wv & 1) * 32;
    const int cb0 = gt * 512 + sl * 64 + jh;   // set0 gate-col base; set1 = +16

    __shared__ __align__(16) u16 h_lds[16 * 512];  // rows 8..15 stay zero
    __shared__ float g_buf[256 * 9];

    // zero h_lds (rows 8-15 feed zero A-rows; rows 0-7 = h(0) = 0)
#pragma unroll
    for (int k = 0; k < 4; ++k) ((u64*)h_lds)[tid + k * 512] = 0ull;

    // register-resident weights: 2 col-sets x 16 k-slices = 128 VGPR
    short8 wf0[16], wf1[16];
    {
        const u16* wp0 = whh + (size_t)(cb0 + (lane & 15)) * 512 + (lane >> 4) * 8;
        const u16* wp1 = wp0 + 16 * 512;
#pragma unroll
        for (int ks = 0; ks < 16; ++ks) {
            wf0[ks] = *(const short8*)(wp0 + ks * 32);
            wf1[ks] = *(const short8*)(wp1 + ks * 32);
        }
    }

    const int b_own = tid >> 6, jj = tid & 63;
    float cst = 0.f;
    u32* pprim = h_ex + (u32)grp * 8192u;
    u32* pmir  = pprim + 65536u;
    const u32 pub_idx = (u32)(b_own * 512 + sl * 64 + jj);
    const int s_c = (tid & 127) >> 4;          // slice producing this thread's poll words
    const bool skip = (s_c == sl);
    const int own_off = b_own * 1024 + (((sl * 64 + jj) * 2) ^ (b_own << 4));

    int lofs[2];
#pragma unroll
    for (int q = 0; q < 2; ++q) {
        int bq = q * 4 + (tid >> 7);
        lofs[q] = bq * 1024 + (((tid & 127) * 8) ^ ((bq & 7) << 4));
    }
    const u16* gpA[4];
    const u16* gpB[4];
#pragma unroll
    for (int i = 0; i < 4; ++i) {
        int bi = ((lane >> 4) & 1) * 4 + i;
        gpA[i] = gx + (size_t)(grp * 8 + bi) * 1024 * 2048 + cb0 + (lane & 15);
        gpB[i] = gpA[i] + 2048;
    }
    u16* routp = rout + (size_t)(grp * 8 + b_own) * 1024 * 512 + sl * 64 + jj;

    // gx double buffers, depth 2 (plain loads; compiler-tracked waitcnt)
    u16 gA[8], gB[8];
#pragma unroll
    for (int i = 0; i < 4; ++i) { gA[2 * i] = gpA[i][0]; gA[2 * i + 1] = gpA[i][16]; }
#pragma unroll
    for (int i = 0; i < 4; ++i) { gB[2 * i] = gpB[i][0]; gB[2 * i + 1] = gpB[i][16]; }

    __syncthreads();  // zeros + wf visible (one-time full drain is fine)

    auto stepbody = [&](u32 t, u16 (&cur)[8], const u16* (&gp)[4]) {
        const u32 part = (t & 1) * 4096u;
        const u32 parn = ((t + 1) & 1) * 4096u;
        // ---- poll: synchronous fused load+wait; sc0 fast path, mirror after 3 misses
        u32x4 qa, qb;
        if (!skip) {
            const u32* pp = pprim + part + tid * 4;
            const u32* pm = pmir + part + tid * 4;
            int tries = 0;
            for (;;) {
                if (tries < 3) poll_sc0(pp, pp + 2048, qa, qb);
                else           poll_sys(pm, pm + 2048, qa, qb);
                u32 bad = 0;
#pragma unroll
                for (int e = 0; e < 4; ++e) {
                    bad |= (qa[e] >> 16) ^ t;
                    bad |= (qb[e] >> 16) ^ t;
                }
                if (!bad) break;
                ++tries;
                if (tries >= 2) __builtin_amdgcn_s_sleep(1);
            }
            // pack payloads -> conflict-free ds_write_b64 (non-own slices only)
            u32 a0 = (qa[0] & 0xffffu) | (qa[1] << 16), a1 = (qa[2] & 0xffffu) | (qa[3] << 16);
            u32 b0 = (qb[0] & 0xffffu) | (qb[1] << 16), b1 = (qb[2] & 0xffffu) | (qb[3] << 16);
            *(u64*)((char*)h_lds + lofs[0]) = (u64)a0 | ((u64)a1 << 32);
            *(u64*)((char*)h_lds + lofs[1]) = (u64)b0 | ((u64)b1 << 32);
        }
        LDS_BARRIER();  // D
        // ---- wave GEMM: 2 col-sets share A-frags; 8 independent chains
        f32x4 a00 = {}, a01 = {}, a02 = {}, a03 = {}, a10 = {}, a11 = {}, a12 = {}, a13 = {};
        {
            const int rowa = lane & 15;
            const int kb0 = (lane >> 4) * 16;
            const int sw = (rowa & 7) << 4;
            const char* rb_ = (const char*)h_lds + rowa * 1024;
#pragma unroll
            for (int kk = 0; kk < 4; ++kk) {
                short8 f0 = *(const short8*)(rb_ + ((kb0 + (4 * kk + 0) * 64) ^ sw));
                short8 f1 = *(const short8*)(rb_ + ((kb0 + (4 * kk + 1) * 64) ^ sw));
                short8 f2 = *(const short8*)(rb_ + ((kb0 + (4 * kk + 2) * 64) ^ sw));
                short8 f3 = *(const short8*)(rb_ + ((kb0 + (4 * kk + 3) * 64) ^ sw));
                a00 = MFMA(f0, wf0[4 * kk + 0], a00); a10 = MFMA(f0, wf1[4 * kk + 0], a10);
                a01 = MFMA(f1, wf0[4 * kk + 1], a01); a11 = MFMA(f1, wf1[4 * kk + 1], a11);
                a02 = MFMA(f2, wf0[4 * kk + 2], a02); a12 = MFMA(f2, wf1[4 * kk + 2], a12);
                a03 = MFMA(f3, wf0[4 * kk + 3], a03); a13 = MFMA(f3, wf1[4 * kk + 3], a13);
            }
        }
        f32x4 acc0 = (a00 + a01) + (a02 + a03);
        f32x4 acc1 = (a10 + a11) + (a12 + a13);
        if ((lane >> 4) < 2) {
            const int lc0 = gt * 64 + jh + (lane & 15);
            const int m0 = (lane >> 4) * 4;
#pragma unroll
            for (int i = 0; i < 4; ++i) {
                g_buf[lc0 * 9 + m0 + i]        = acc0[i] + bf2f((u16)cur[2 * i]);
                g_buf[(lc0 + 16) * 9 + m0 + i] = acc1[i] + bf2f((u16)cur[2 * i + 1]);
            }
        }
        // ---- gx prefetch for t+2 (after last use of cur; compiler-managed waits)
        if (t < 1022) {
#pragma unroll
            for (int i = 0; i < 4; ++i) gp[i] += 4096;
        }
#pragma unroll
        for (int i = 0; i < 4; ++i) { cur[2 * i] = gp[i][0]; cur[2 * i + 1] = gp[i][16]; }
        LDS_BARRIER();  // F
        // ---- gates + state update; own h -> LDS; publish prim/mirror/rout
        {
            float iv = g_buf[(jj) * 9 + b_own];
            float fv = g_buf[(jj + 64) * 9 + b_own];
            float gv = g_buf[(jj + 128) * 9 + b_own];
            float ov = g_buf[(jj + 192) * 9 + b_own];
            cst = sigm(fv) * cst + sigm(iv) * tanh_f(gv);
            float h = sigm(ov) * tanh_f(cst);
            u32 hb = (u32)f2bf(h);
            *(u16*)((char*)h_lds + own_off) = (u16)hb;
            u32 w = ((t + 1) << 16) | hb;
            cstore_sc0(pprim + parn + pub_idx, w);
            cstore_sys(pmir + parn + pub_idx, w);
            store_short(routp, hb);
            routp += 512;
        }
    };

    for (u32 t = 0; t < 1024; t += 2) {
        stepbody(t, gA, gpA);
        stepbody(t + 1, gB, gpB);
    }
}

// ---------- launch ----------
extern "C" void kernel_launch(void* const* d_in, const int* in_sizes, int n_in,
                              void* d_out, int out_size, void* d_ws, size_t ws_size,
                              hipStream_t stream) {
    const float* x     = (const float*)d_in[0];
    const float* pre_g = (const float*)d_in[1];
    const float* pre_b = (const float*)d_in[2];
    const float* w_ih  = (const float*)d_in[3];
    const float* w_hh  = (const float*)d_in[4];
    const float* b_ih  = (const float*)d_in[5];
    const float* b_hh  = (const float*)d_in[6];
    const float* post_g= (const float*)d_in[7];
    const float* post_b= (const float*)d_in[8];
    const float* w1    = (const float*)d_in[9];
    const float* b1    = (const float*)d_in[10];
    const float* w2    = (const float*)d_in[11];
    const float* b2    = (const float*)d_in[12];
    float* out = (float*)d_out;

    char* p = (char*)d_ws;
    auto carve = [&](size_t bytes) { void* r = (void*)p; p += (bytes + 255) & ~(size_t)255; return r; };
    u16* xln   = (u16*)carve(64ull * 1024 * 512 * 2);    // 64 MiB; reused as ln1 after GEMM1
    u16* gxb   = (u16*)carve(64ull * 1024 * 2048 * 2);   // 256 MiB; reused as h1 after scan
    u16* rb    = (u16*)carve(64ull * 1024 * 512 * 2);    // 64 MiB
    u16* wihb  = (u16*)carve(2048ull * 512 * 2);
    u16* whhb  = (u16*)carve(2048ull * 512 * 2);
    u16* w1t   = (u16*)carve(1024ull * 512 * 2);
    u16* w2t   = (u16*)carve(512ull * 1024 * 2);
    float* biasc = (float*)carve(2048ull * 4);
    u32* h_ex  = (u32*)carve(131072ull * 4);             // primary 64K + mirror 64K tagged u32
    u16* ln1 = xln;   // alias: xln dead after GEMM1
    u16* h1  = gxb;   // alias: gx dead after scan

    k_prep<<<3072, 256, 0, stream>>>(w_ih, w_hh, b_ih, b_hh, w1, w2, wihb, whhb, w1t, w2t, biasc);
    k_init<<<512, 256, 0, stream>>>(h_ex);
    k_pre_ln<<<16384, 256, 0, stream>>>(x, pre_g, pre_b, xln);
    k_gemm<512, 0><<<dim3(16, 512), 256, 0, stream>>>(xln, wihb, biasc, gxb, nullptr, nullptr, nullptr, 2048);
    k_scan<<<64, 512, 0, stream>>>(gxb, whhb, rb, h_ex);
    k_res_ln<<<16384, 256, 0, stream>>>(x, rb, post_g, post_b, ln1);
    k_gemm<512, 1><<<dim3(8, 512), 256, 0, stream>>>(ln1, w1t, b1, h1, nullptr, nullptr, nullptr, 1024);
    k_gemm<1024, 2><<<dim3(4, 512), 256, 0, stream>>>(h1, w2t, b2, nullptr, out, x, rb, 512);
}